// Round 4
// baseline (122.451 us; speedup 1.0000x reference)
//
#include <hip/hip_runtime.h>

// CatmullRomActivation — MI355X (gfx950), round 4: pipeline across tiles.
//
// Reference quirk: coef is sample-major flat, Q is neuron-major flat, multiplied
// on the same linear index q. So for out.flat[q]:
//   u-part   : x.flat[q]                     (linear, coalesced)
//   p0/points: x[iq][jq], jq=q/M, iq=q%M     (transposed traversal, cp row jq)
//
// R3 (~38 us) showed one-tile-per-block can't hide cold-load latency: every
// block pays stage->vmcnt(0)->barrier->read->compute serially, once, then dies.
// R4: each block owns 4 iq-tiles of one jq-column. Per tile, after the
// transposed values are batched into registers, the SECOND barrier frees xt
// immediately and the NEXT tile's global loads (tile + linear) are issued
// before compute -- a full compute+store phase hides their latency.
// cp staging amortized 4x. Grid (32,32)=1024 blocks -> 4 blocks/CU, 16 waves.

constexpr int M_DIM = 8192;   // samples
constexpr int N_DIM = 2048;   // neurons
constexpr int KPTS  = 10;     // control points per neuron
constexpr int TILE  = 64;
constexpr int PITCH = TILE + 1;  // 65: transposed reads max 2-way (free, m136)
constexpr int NTILE = 4;      // iq-tiles per block

typedef float floatx4 __attribute__((ext_vector_type(4)));

__global__ __launch_bounds__(256)
void catmull_rom_kernel(const float* __restrict__ x,
                        const float* __restrict__ cp,
                        float* __restrict__ out)
{
    __shared__ float xt[TILE * PITCH];     // xt[r*PITCH+c] = x[iq0+r][jq0+c]
    __shared__ float cps[TILE * KPTS];     // cps[c*KPTS+k] = cp[jq0+c][k]

    const int t   = threadIdx.x;
    const int jq0 = blockIdx.y * TILE;
    const int iqb = blockIdx.x * (TILE * NTILE);

    // ---- cp loads (once per block, 640 floats) ----
    const float* cpb = cp + (size_t)jq0 * KPTS;
    float cv0 = cpb[t];
    float cv1 = cpb[t + 256];
    float cv2 = (t < TILE * KPTS - 512) ? cpb[t + 512] : 0.0f;

    // ---- prefetch tile 0: transposed-source tile + linear x ----
    const float* xtile = x + (size_t)iqb * N_DIM;
    float4 tv[4], xl[4];
    size_t qb[4];
    #pragma unroll
    for (int k = 0; k < 4; ++k) {
        int f = t + k * 256;
        int r = f >> 4, c4 = (f & 15) << 2;
        tv[k] = *reinterpret_cast<const float4*>(
            xtile + (size_t)r * N_DIM + (jq0 + c4));
    }
    #pragma unroll
    for (int k = 0; k < 4; ++k) {
        int f  = t + k * 256;
        int tj = f >> 4, g = (f & 15) << 2;
        qb[k] = (size_t)(jq0 + tj) * M_DIM + (size_t)(iqb + g);
        xl[k] = *reinterpret_cast<const float4*>(x + qb[k]);
    }
    cps[t]       = cv0;
    cps[t + 256] = cv1;
    if (t < TILE * KPTS - 512) cps[t + 512] = cv2;

    for (int tile = 0; tile < NTILE; ++tile) {
        // ---- stage current tile to LDS ----
        #pragma unroll
        for (int k = 0; k < 4; ++k) {
            int f = t + k * 256;
            int r = f >> 4, c4 = (f & 15) << 2;
            float* dst = &xt[r * PITCH + c4];
            dst[0] = tv[k].x; dst[1] = tv[k].y; dst[2] = tv[k].z; dst[3] = tv[k].w;
        }
        __syncthreads();

        // ---- batch the 16 transposed reads, then free xt immediately ----
        float xq[16];
        #pragma unroll
        for (int k = 0; k < 4; ++k) {
            int f = t + k * 256;
            int tj = f >> 4, g = (f & 15) << 2;
            #pragma unroll
            for (int e = 0; e < 4; ++e)
                xq[k * 4 + e] = xt[(g + e) * PITCH + tj];
        }
        __syncthreads();   // xt free; next staging needs no further barrier

        // ---- issue next tile's global loads BEFORE compute ----
        float4 xln[4];
        if (tile + 1 < NTILE) {
            const float* xtn = xtile + (size_t)(tile + 1) * TILE * N_DIM;
            #pragma unroll
            for (int k = 0; k < 4; ++k) {
                int f = t + k * 256;
                int r = f >> 4, c4 = (f & 15) << 2;
                tv[k] = *reinterpret_cast<const float4*>(
                    xtn + (size_t)r * N_DIM + (jq0 + c4));
            }
            #pragma unroll
            for (int k = 0; k < 4; ++k)
                xln[k] = *reinterpret_cast<const float4*>(
                    x + qb[k] + (size_t)(tile + 1) * TILE);
        }

        // ---- compute + store (hides the prefetch latency) ----
        #pragma unroll
        for (int k = 0; k < 4; ++k) {
            int f  = t + k * 256;
            int tj = f >> 4;
            const float* cpn = &cps[tj * KPTS];
            float xle[4] = {xl[k].x, xl[k].y, xl[k].z, xl[k].w};
            float res[4];
            #pragma unroll
            for (int e = 0; e < 4; ++e) {
                float xv_t = xq[k * 4 + e];
                float p0f  = floorf((xv_t + 2.0f) * 1.5f + 1.0f);   // == *6/4
                int   p0   = (int)p0f;
                p0 = (xv_t <= -2.0f) ? 1 : p0;
                p0 = (xv_t >=  2.0f) ? 7 : p0;

                float Pm1 = cpn[p0 - 1];
                float P0  = cpn[p0];
                float P1  = cpn[p0 + 1];
                float P2  = cpn[p0 + 2];

                float xv = xle[e];
                float tt = 2.0f * xv;            // x / 0.5
                float u  = tt - floorf(tt);
                float u2 = u * u;
                float u3 = u2 * u;
                float c0 = -0.5f*u3 +       u2 - 0.5f*u;   // pairs P2
                float c1 =  1.5f*u3 - 2.5f*u2 + 1.0f;      // pairs P1
                float c2 = -1.5f*u3 + 2.0f*u2 + 0.5f*u;    // pairs P0
                float c3 =  0.5f*u3 - 0.5f*u2;             // pairs Pm1
                res[e] = c3*Pm1 + c2*P0 + c1*P1 + c0*P2;
            }
            floatx4 ov = {res[0], res[1], res[2], res[3]};
            __builtin_nontemporal_store(
                ov, reinterpret_cast<floatx4*>(out + qb[k] + (size_t)tile * TILE));
        }

        #pragma unroll
        for (int k = 0; k < 4; ++k) xl[k] = xln[k];
    }
}

extern "C" void kernel_launch(void* const* d_in, const int* in_sizes, int n_in,
                              void* d_out, int out_size, void* d_ws, size_t ws_size,
                              hipStream_t stream) {
    const float* x  = (const float*)d_in[0];   // (M, N) f32
    const float* cp = (const float*)d_in[1];   // (N, K) f32
    float* out = (float*)d_out;                // (M, N) f32

    dim3 grid(M_DIM / (TILE * NTILE), N_DIM / TILE);   // (32, 32)
    dim3 block(256);
    catmull_rom_kernel<<<grid, block, 0, stream>>>(x, cp, out);
}